// Round 6
// baseline (1132.872 us; speedup 1.0000x reference)
//
#include <hip/hip_runtime.h>
#include <hip/hip_bf16.h>
#include <cstdint>
#include <cstddef>

using bf16_t = __hip_bfloat16;
typedef __bf16 bf16x8 __attribute__((ext_vector_type(8)));
typedef __bf16 bf16x4 __attribute__((ext_vector_type(4)));
typedef float f32x4 __attribute__((ext_vector_type(4)));

#define DEVI static __device__ __forceinline__

DEVI float b2f(bf16_t v) { return __bfloat162float(v); }

DEVI float fsigmoid(float x) { return 1.0f / (1.0f + __expf(-x)); }
DEVI float fsilu(float x) { return x * fsigmoid(x); }
DEVI float fgelu(float x) { return 0.5f * x * (1.0f + erff(x * 0.70710678118654752440f)); }

// async global->LDS, 16B per lane; LDS dest = wave-uniform base + lane*16
DEVI void g2l16(const bf16_t* g, bf16_t* l) {
    __builtin_amdgcn_global_load_lds(
        (const __attribute__((address_space(1))) void*)g,
        (__attribute__((address_space(3))) void*)l,
        16, 0, 0);
}

// ---------------------------------------------------------------------------
// NT GEMM, BK=32, 16x16x32 MFMA (R3-proven core: 0 bank conflicts, coalesced
// vector epilogue): C[M,N] = A[M,K] @ B[N,K]^T (+bias) (act) (+resid).
// bf16 row-major. M,N % 128 == 0, K % 32 == 0. Batched via grid.z.
// MFMA operands swapped (B-frag first) -> lane holds 4 consecutive cols.
// LDS XOR swizzle slot = chunk ^ swz on staging and fragment reads.
// ACT: 0 none, 1 gelu, 3 qkv-mix (seg 0/1 silu, 2 gelu, 3 sigmoid*0.9+0.1)
// QKVSPLIT: col segments of 1536 -> seg-major output (sC = seg stride).
// ---------------------------------------------------------------------------
template<int ACT, bool RESID, bool OUTBF, bool QKVSPLIT>
__global__ __launch_bounds__(256) void gemm_nt(
    const bf16_t* __restrict__ A, const bf16_t* __restrict__ B,
    void* __restrict__ Cout, const float* __restrict__ bias,
    const float* __restrict__ resid,
    int M, int N, int K, long long sA, long long sB, long long sC)
{
    __shared__ bf16_t As[128 * 32];
    __shared__ bf16_t Bs[128 * 32];

    const int t  = threadIdx.x;
    const int w  = t >> 6;
    const int ln = t & 63;
    const long long bz = blockIdx.z;
    A += bz * sA;
    B += bz * sB;
    const long long cbase = QKVSPLIT ? 0 : bz * sC;

    const int m0 = blockIdx.y * 128;
    const int n0 = blockIdx.x * 128;
    const int wm = (w >> 1) * 64;
    const int wn = (w & 1) * 64;

    f32x4 acc[4][4] = {};

    // staging: lane covers tile row base+(ln>>2), slot (ln&3);
    // slot s holds global chunk s ^ ((row>>1)&3) = s ^ ((ln>>3)&3).
    const int rI0 = (w * 2 + 0) * 16 + (ln >> 2);
    const int rI1 = (w * 2 + 1) * 16 + (ln >> 2);
    const int kc8 = (((ln & 3) ^ ((ln >> 3) & 3)) * 8);
    bf16_t* ldsA0 = &As[(w * 2 + 0) * 512];
    bf16_t* ldsA1 = &As[(w * 2 + 1) * 512];
    bf16_t* ldsB0 = &Bs[(w * 2 + 0) * 512];
    bf16_t* ldsB1 = &Bs[(w * 2 + 1) * 512];

    // fragment read: row fr=ln&15, chunk c=ln>>4; slot = c ^ ((fr>>1)&3)
    const int fr = ln & 15;
    const int koff = (((ln >> 4) ^ ((ln >> 1) & 3)) * 8);

    for (int k0 = 0; k0 < K; k0 += 32) {
        g2l16(A + (size_t)(m0 + rI0) * K + k0 + kc8, ldsA0);
        g2l16(A + (size_t)(m0 + rI1) * K + k0 + kc8, ldsA1);
        g2l16(B + (size_t)(n0 + rI0) * K + k0 + kc8, ldsB0);
        g2l16(B + (size_t)(n0 + rI1) * K + k0 + kc8, ldsB1);
        __syncthreads();

        bf16x8 af[4], bfr[4];
#pragma unroll
        for (int i = 0; i < 4; ++i) {
            af[i]  = *(const bf16x8*)&As[(wm + i * 16 + fr) * 32 + koff];
            bfr[i] = *(const bf16x8*)&Bs[(wn + i * 16 + fr) * 32 + koff];
        }
#pragma unroll
        for (int mi = 0; mi < 4; ++mi)
#pragma unroll
            for (int ni = 0; ni < 4; ++ni)
                acc[mi][ni] = __builtin_amdgcn_mfma_f32_16x16x32_bf16(
                    bfr[ni], af[mi], acc[mi][ni], 0, 0, 0);   // swapped
        __syncthreads();
    }

    // epilogue: lane holds C[row = wm+mi*16+fr][cols = wn+ni*16+qd*4 .. +3]
    const int rb = (ln >> 4) * 4;
    const int seg = QKVSPLIT ? (n0 / 1536) : 0;
    f32x4 bias4[4];
#pragma unroll
    for (int ni = 0; ni < 4; ++ni) {
        f32x4 z = {};
        bias4[ni] = bias ? *(const f32x4*)&bias[n0 + wn + ni * 16 + rb] : z;
    }
#pragma unroll
    for (int mi = 0; mi < 4; ++mi) {
        const int row = m0 + wm + mi * 16 + fr;
#pragma unroll
        for (int ni = 0; ni < 4; ++ni) {
            const int col0 = n0 + wn + ni * 16 + rb;
            f32x4 v = acc[mi][ni] + bias4[ni];
            if constexpr (ACT == 1) {
#pragma unroll
                for (int r = 0; r < 4; ++r) v[r] = fgelu(v[r]);
            }
            if constexpr (ACT == 3) {
                if (seg <= 1) {
#pragma unroll
                    for (int r = 0; r < 4; ++r) v[r] = fsilu(v[r]);
                } else if (seg == 2) {
#pragma unroll
                    for (int r = 0; r < 4; ++r) v[r] = fgelu(v[r]);
                } else {
#pragma unroll
                    for (int r = 0; r < 4; ++r) v[r] = fsigmoid(v[r]) * 0.9f + 0.1f;
                }
            }
            long long off;
            if constexpr (QKVSPLIT) {
                off = (long long)seg * sC + (long long)row * 1536
                    + (col0 - seg * 1536);
            } else {
                off = cbase + (long long)row * N + col0;
            }
            if constexpr (RESID) v += *(const f32x4*)&resid[off];
            if constexpr (OUTBF) {
                bf16x4 o;
#pragma unroll
                for (int r = 0; r < 4; ++r) o[r] = (__bf16)v[r];
                *(bf16x4*)((bf16_t*)Cout + off) = o;
            } else {
                *(f32x4*)((float*)Cout + off) = v;
            }
        }
    }
}

// ---------------------------------------------------------------------------
// LayerNorm f32 -> bf16, n = NT*4, one block per row.
// ---------------------------------------------------------------------------
template<int NT>
__global__ __launch_bounds__(NT) void ln_v4(
    const float* __restrict__ x, const float* __restrict__ g,
    const float* __restrict__ b, bf16_t* __restrict__ out)
{
    constexpr int n = NT * 4;
    constexpr int NW = NT / 64;
    const int row = blockIdx.x, t = threadIdx.x;
    f32x4 v = *(const f32x4*)&x[(size_t)row * n + t * 4];
    float s  = v[0] + v[1] + v[2] + v[3];
    float ss = v[0]*v[0] + v[1]*v[1] + v[2]*v[2] + v[3]*v[3];
#pragma unroll
    for (int m = 32; m; m >>= 1) { s += __shfl_xor(s, m, 64); ss += __shfl_xor(ss, m, 64); }
    __shared__ float red[2 * NW];
    const int w = t >> 6;
    if ((t & 63) == 0) { red[w] = s; red[NW + w] = ss; }
    __syncthreads();
    s = 0.f; ss = 0.f;
#pragma unroll
    for (int i = 0; i < NW; ++i) { s += red[i]; ss += red[NW + i]; }
    const float mean = s / n;
    const float rstd = rsqrtf(ss / n - mean * mean + 1e-5f);
    const f32x4 gv = *(const f32x4*)&g[t * 4];
    const f32x4 bv = *(const f32x4*)&b[t * 4];
    bf16x4 o;
#pragma unroll
    for (int r = 0; r < 4; ++r)
        o[r] = (__bf16)((v[r] - mean) * rstd * gv[r] + bv[r]);
    *(bf16x4*)&out[(size_t)row * n + t * 4] = o;
}

// ---------------------------------------------------------------------------
// LayerNorm bf16 -> bf16 over 1536 (with scalar pre-scale). 192 thr x 8.
// ---------------------------------------------------------------------------
__global__ __launch_bounds__(192) void ln_bf16_1536(
    const bf16_t* __restrict__ x, const float* __restrict__ g,
    const float* __restrict__ b, bf16_t* __restrict__ out,
    const float* __restrict__ scale_ptr)
{
    const int row = blockIdx.x, t = threadIdx.x;
    const float scale = scale_ptr[0];
    const bf16x8 x8 = *(const bf16x8*)&x[(size_t)row * 1536 + t * 8];
    float v[8];
    float s = 0.f, ss = 0.f;
#pragma unroll
    for (int i = 0; i < 8; ++i) {
        v[i] = (float)x8[i] * scale;
        s += v[i]; ss += v[i] * v[i];
    }
#pragma unroll
    for (int m = 32; m; m >>= 1) { s += __shfl_xor(s, m, 64); ss += __shfl_xor(ss, m, 64); }
    __shared__ float red[6];
    const int w = t >> 6;
    if ((t & 63) == 0) { red[w] = s; red[3 + w] = ss; }
    __syncthreads();
    s  = red[0] + red[1] + red[2];
    ss = red[3] + red[4] + red[5];
    const float mean = s / 1536.f;
    const float rstd = rsqrtf(ss / 1536.f - mean * mean + 1e-5f);
    const f32x4 g0 = *(const f32x4*)&g[t * 8];
    const f32x4 g1 = *(const f32x4*)&g[t * 8 + 4];
    const f32x4 b0 = *(const f32x4*)&b[t * 8];
    const f32x4 b1 = *(const f32x4*)&b[t * 8 + 4];
    bf16x8 o;
#pragma unroll
    for (int r = 0; r < 4; ++r) {
        o[r]     = (__bf16)((v[r]     - mean) * rstd * g0[r] + b0[r]);
        o[r + 4] = (__bf16)((v[r + 4] - mean) * rstd * g1[r] + b1[r]);
    }
    *(bf16x8*)&out[(size_t)row * 1536 + t * 8] = o;
}

// ---------------------------------------------------------------------------
// Per-token l2 norms of already-silu'd q,k: norms[tok] = {1/||q||, 1/||k||}.
// ---------------------------------------------------------------------------
__global__ __launch_bounds__(192) void qk_norms(
    const bf16_t* __restrict__ q, const bf16_t* __restrict__ k,
    float2* __restrict__ norms)
{
    const int row = blockIdx.x, t = threadIdx.x;
    const bf16x8 q8 = *(const bf16x8*)&q[(size_t)row * 1536 + t * 8];
    const bf16x8 k8 = *(const bf16x8*)&k[(size_t)row * 1536 + t * 8];
    float sq = 0.f, sk = 0.f;
#pragma unroll
    for (int i = 0; i < 8; ++i) {
        const float a = (float)q8[i];
        const float c = (float)k8[i];
        sq += a * a; sk += c * c;
    }
#pragma unroll
    for (int m = 32; m; m >>= 1) { sq += __shfl_xor(sq, m, 64); sk += __shfl_xor(sk, m, 64); }
    __shared__ float red[6];
    const int w = t >> 6;
    if ((t & 63) == 0) { red[w] = sq; red[3 + w] = sk; }
    __syncthreads();
    if (t == 0) {
        sq = red[0] + red[1] + red[2];
        sk = red[3] + red[4] + red[5];
        float2 o;
        o.x = 1.0f / fmaxf(sqrtf(sq), 1e-12f);
        o.y = 1.0f / fmaxf(sqrtf(sk), 1e-12f);
        norms[row] = o;
    }
}

// ---------------------------------------------------------------------------
// Fused q+k coupling + depthwise conv (k=3, pad 1).
// Inputs qs,ks already silu'd. q1 = qs*rq + 0.1*ks; k1 = ks*rk + 0.1*q1.
// conv both; qc natural [B,L,E], kT transposed [B,E,L].
// grid (E/64, L/64, B), block 256; thread = 4e x 4l.
// ---------------------------------------------------------------------------
__global__ __launch_bounds__(256) void ac_qk(
    const bf16_t* __restrict__ qs, const bf16_t* __restrict__ ks,
    const float2* __restrict__ norms,
    bf16_t* __restrict__ qc, bf16_t* __restrict__ kT,
    const float* __restrict__ cw)
{
    constexpr int L = 4096, E = 1536;
    const int b = blockIdx.z;
    const int e0 = blockIdx.x * 64, l0 = blockIdx.y * 64;
    const int t = threadIdx.x;
    const int e = e0 + (t & 15) * 4;
    const int lbase = l0 + (t >> 4) * 4;
    const size_t rowL = (size_t)b * L;

    float w0[4], w1[4], w2[4];
#pragma unroll
    for (int i = 0; i < 4; ++i) {
        w0[i] = cw[(e + i) * 3 + 0];
        w1[i] = cw[(e + i) * 3 + 1];
        w2[i] = cw[(e + i) * 3 + 2];
    }

    float sq[6][4], sk[6][4];
#pragma unroll
    for (int j = 0; j < 6; ++j) {
        const int l = lbase - 1 + j;
        if (l < 0 || l >= L) {
#pragma unroll
            for (int i = 0; i < 4; ++i) { sq[j][i] = 0.f; sk[j][i] = 0.f; }
            continue;
        }
        const size_t off = (rowL + l) * E + e;
        const bf16x4 q4 = *(const bf16x4*)&qs[off];
        const bf16x4 k4 = *(const bf16x4*)&ks[off];
        const float2 nm = norms[rowL + l];
#pragma unroll
        for (int i = 0; i < 4; ++i) {
            const float q1 = (float)q4[i] * nm.x + 0.1f * (float)k4[i];
            const float k1 = (float)k4[i] * nm.y + 0.1f * q1;
            sq[j][i] = q1; sk[j][i] = k1;
        }
    }

#pragma unroll
    for (int j = 0; j < 4; ++j) {
        bf16x4 oq;
#pragma unroll
        for (int i = 0; i < 4; ++i)
            oq[i] = (__bf16)(w0[i] * sq[j][i] + w1[i] * sq[j + 1][i] + w2[i] * sq[j + 2][i]);
        *(bf16x4*)&qc[(rowL + lbase + j) * E + e] = oq;
    }
#pragma unroll
    for (int i = 0; i < 4; ++i) {
        bf16x4 ok;
#pragma unroll
        for (int j = 0; j < 4; ++j)
            ok[j] = (__bf16)(w0[i] * sk[j][i] + w1[i] * sk[j + 1][i] + w2[i] * sk[j + 2][i]);
        *(bf16x4*)&kT[((size_t)b * E + e + i) * L + lbase] = ok;
    }
}

// ---------------------------------------------------------------------------
// v stream: conv(gelu'd v) * beta' -> transposed [B,E,L].
// ---------------------------------------------------------------------------
__global__ __launch_bounds__(256) void ac_v(
    const bf16_t* __restrict__ vg, const bf16_t* __restrict__ beta,
    bf16_t* __restrict__ vT, const float* __restrict__ cw)
{
    constexpr int L = 4096, E = 1536;
    const int b = blockIdx.z;
    const int e0 = blockIdx.x * 64, l0 = blockIdx.y * 64;
    const int t = threadIdx.x;
    const int e = e0 + (t & 15) * 4;
    const int lbase = l0 + (t >> 4) * 4;
    const size_t rowL = (size_t)b * L;

    float w0[4], w1[4], w2[4];
#pragma unroll
    for (int i = 0; i < 4; ++i) {
        w0[i] = cw[(e + i) * 3 + 0];
        w1[i] = cw[(e + i) * 3 + 1];
        w2[i] = cw[(e + i) * 3 + 2];
    }

    float s[6][4];
#pragma unroll
    for (int j = 0; j < 6; ++j) {
        const int l = lbase - 1 + j;
        if (l < 0 || l >= L) {
#pragma unroll
            for (int i = 0; i < 4; ++i) s[j][i] = 0.f;
            continue;
        }
        const bf16x4 v4 = *(const bf16x4*)&vg[(rowL + l) * E + e];
#pragma unroll
        for (int i = 0; i < 4; ++i) s[j][i] = (float)v4[i];
    }

    float o[4][4];
#pragma unroll
    for (int j = 0; j < 4; ++j) {
        const bf16x4 b4 = *(const bf16x4*)&beta[(rowL + lbase + j) * E + e];
#pragma unroll
        for (int i = 0; i < 4; ++i)
            o[j][i] = (w0[i] * s[j][i] + w1[i] * s[j + 1][i] + w2[i] * s[j + 2][i])
                      * (float)b4[i];
    }
#pragma unroll
    for (int i = 0; i < 4; ++i) {
        bf16x4 ov;
#pragma unroll
        for (int j = 0; j < 4; ++j) ov[j] = (__bf16)o[j][i];
        *(bf16x4*)&vT[((size_t)b * E + e + i) * L + lbase] = ov;
    }
}

// ---------------------------------------------------------------------------
// prep1: cast W_in|W_beta -> Wcat (contiguous), copy b_in|b_beta -> bcat.
// ---------------------------------------------------------------------------
__global__ __launch_bounds__(256) void prep1(
    const float* __restrict__ Win, const float* __restrict__ Wbeta,
    const float* __restrict__ bin, const float* __restrict__ bbeta,
    bf16_t* __restrict__ Wcat, float* __restrict__ bcat)
{
    constexpr int nWin4 = 3 * 1536 * 768 / 4;   // 884736
    constexpr int nWb4  = 1536 * 768 / 4;       // 294912
    const int i = blockIdx.x * 256 + threadIdx.x;
    if (i < nWin4) {
        const f32x4 v = ((const f32x4*)Win)[i];
        bf16x4 o;
#pragma unroll
        for (int r = 0; r < 4; ++r) o[r] = (__bf16)v[r];
        ((bf16x4*)Wcat)[i] = o;
    } else if (i < nWin4 + nWb4) {
        const f32x4 v = ((const f32x4*)Wbeta)[i - nWin4];
        bf16x4 o;
#pragma unroll
        for (int r = 0; r < 4; ++r) o[r] = (__bf16)v[r];
        ((bf16x4*)Wcat)[i] = o;
    } else {
        const int j = i - nWin4 - nWb4;         // 0..1535
        ((f32x4*)bcat)[j] = (j < 1152) ? ((const f32x4*)bin)[j]
                                       : ((const f32x4*)bbeta)[j - 1152];
    }
}

// prep2: cast W_out|W1|W2 into one contiguous bf16 region. 5760 blocks exact.
__global__ __launch_bounds__(256) void prep2(
    const float* __restrict__ Wout, const float* __restrict__ W1,
    const float* __restrict__ W2, bf16_t* __restrict__ dst)
{
    constexpr int n0 = 768 * 1536 / 4;          // 294912
    constexpr int n1 = n0 + 3072 * 768 / 4;     // + 589824
    const int i = blockIdx.x * 256 + threadIdx.x;
    const float* src;
    int j;
    if (i < n0)      { src = Wout; j = i; }
    else if (i < n1) { src = W1;   j = i - n0; }
    else             { src = W2;   j = i - n1; }
    const f32x4 v = ((const f32x4*)src)[j];
    bf16x4 o;
#pragma unroll
    for (int r = 0; r < 4; ++r) o[r] = (__bf16)v[r];
    ((bf16x4*)dst)[i] = o;
}

// diagnostic: report ws_size via absmax error channel
__global__ void diag_ws(float* o, float v) { o[threadIdx.x] = v; }

// ---------------------------------------------------------------------------

extern "C" void kernel_launch(void* const* d_in, const int* in_sizes, int n_in,
                              void* d_out, int out_size, void* d_ws, size_t ws_size,
                              hipStream_t stream)
{
    constexpr int B = 4, L = 4096, H = 768, E = 1536;
    constexpr int T = B * L;
    constexpr size_t SEGE = (size_t)T * E;
    constexpr size_t S    = SEGE * 2;            // 50,331,648 B
    constexpr size_t o_bcat  = 5 * S;
    constexpr size_t o_norms = o_bcat + 6144 * 4;
    constexpr size_t WS_NEED = o_norms + (size_t)T * 8;

    const float* x       = (const float*)d_in[0];
    const float* ln1_g   = (const float*)d_in[1];
    const float* ln1_b   = (const float*)d_in[2];
    const float* ln2_g   = (const float*)d_in[3];
    const float* ln2_b   = (const float*)d_in[4];
    const float* W_in    = (const float*)d_in[5];
    const float* b_in    = (const float*)d_in[6];
    const float* W_beta  = (const float*)d_in[7];
    const float* b_beta  = (const float*)d_in[8];
    const float* W_out   = (const float*)d_in[9];
    const float* b_out   = (const float*)d_in[10];
    const float* W1      = (const float*)d_in[11];
    const float* b1      = (const float*)d_in[12];
    const float* W2      = (const float*)d_in[13];
    const float* b2      = (const float*)d_in[14];
    const float* conv_w  = (const float*)d_in[15];
    const float* attn_sc = (const float*)d_in[16];

    if (ws_size < WS_NEED) {
        diag_ws<<<1, 256, 0, stream>>>((float*)d_out,
                                       10000.0f + (float)(ws_size >> 20));
        return;
    }

    char* ws = (char*)d_ws;
    bf16_t* slotA = (bf16_t*)(ws + 0 * S);   // qs -> state[0:18.9M] + weights@20M
    bf16_t* slotB = (bf16_t*)(ws + 1 * S);   // ks -> attn(bf16) -> xn2
    bf16_t* slotC = (bf16_t*)(ws + 2 * S);   // vg -> kT -> x2(f32)
    bf16_t* slotD = (bf16_t*)(ws + 3 * S);   // beta' -> qc -> h1[first half]
    bf16_t* slotE = (bf16_t*)(ws + 4 * S);   // Wcat+xn -> vT -> ln2o -> h1[2nd]
    float*  bcat  = (float*)(ws + o_bcat);
    float2* norms = (float2*)(ws + o_norms);

    bf16_t* Wcat = slotE;                                           // 9.44 MB
    bf16_t* xn   = (bf16_t*)((char*)slotE + (size_t)6144 * H * 2);  // 25.2 MB

    bf16_t* vT    = slotE;                   // [B,E,L]
    bf16_t* kT    = slotC;                   // [B,E,L]
    bf16_t* qc    = slotD;                   // [B,L,E]
    bf16_t* state = slotA;                   // [B,E,E] 18.9 MB
    bf16_t* WoutB = (bf16_t*)((char*)slotA + (size_t)20 * 1024 * 1024);
    bf16_t* W1B   = WoutB + (size_t)H * E;
    bf16_t* W2B   = W1B + (size_t)4 * H * H;
    bf16_t* attn  = slotB;                   // [T,E] bf16
    bf16_t* ln2o  = slotE;                   // [T,E] bf16
    float*  x2    = (float*)slotC;           // [T,768] f32
    bf16_t* xn2   = slotB;                   // [T,768] bf16
    bf16_t* h1    = slotD;                   // [T,3072] bf16 spans D+E

    // ---- 0. weight prep (phase 1) ----
    prep1<<<4614, 256, 0, stream>>>(W_in, W_beta, b_in, b_beta, Wcat, bcat);

    // ---- 1. ln1(x) -> xn ----
    ln_v4<192><<<T, 192, 0, stream>>>(x, ln1_g, ln1_b, xn);

    // ---- 2. fused qkv+beta GEMM, activations in epilogue, seg-major out ----
    gemm_nt<3, false, true, true><<<dim3(6144 / 128, T / 128, 1), 256, 0, stream>>>(
        xn, Wcat, slotA, bcat, nullptr, T, 6144, H, 0, 0, (long long)SEGE);

    // ---- 3. per-token l2 norms of silu'd q,k ----
    qk_norms<<<T, 192, 0, stream>>>(slotA, slotB, norms);

    // ---- 4. conv streams: v first (frees C,D), then fused q+k ----
    ac_v <<<dim3(E / 64, L / 64, B), 256, 0, stream>>>(slotC, slotD, vT, conv_w);
    ac_qk<<<dim3(E / 64, L / 64, B), 256, 0, stream>>>(slotA, slotB, norms, qc, kT, conv_w);

    // ---- 5. weight prep (phase 2) into dead slot-A tail ----
    prep2<<<5760, 256, 0, stream>>>(W_out, W1, W2, WoutB);

    // ---- 6. state[b,e,f] = sum_l vnew[b,e,l] k[b,f,l] ----
    gemm_nt<0, false, true, false><<<dim3(E / 128, E / 128, B), 256, 0, stream>>>(
        vT, kT, state, nullptr, nullptr, E, E, L,
        (long long)E * L, (long long)E * L, (long long)E * E);

    // ---- 7. attn[b,l,e] = sum_f q[b,l,f] state[b,e,f] (bf16 out) ----
    gemm_nt<0, false, true, false><<<dim3(E / 128, L / 128, B), 256, 0, stream>>>(
        qc, state, attn, nullptr, nullptr, L, E, E,
        (long long)L * E, (long long)E * E, (long long)L * E);

    // ---- 8. ln2(attn * attn_scale) ----
    ln_bf16_1536<<<T, 192, 0, stream>>>(attn, ln2_g, ln2_b, ln2o, attn_sc);

    // ---- 9. x2 = x + ln2o @ W_out^T + b_out ----
    gemm_nt<0, true, false, false><<<dim3(H / 128, T / 128, 1), 256, 0, stream>>>(
        ln2o, WoutB, x2, b_out, x, T, H, E, 0, 0, 0);

    // ---- 10. ln1(x2) -> xn2 ----
    ln_v4<192><<<T, 192, 0, stream>>>(x2, ln1_g, ln1_b, xn2);

    // ---- 11. h1 = gelu(xn2 @ W1^T + b1) ----
    gemm_nt<1, false, true, false><<<dim3(4 * H / 128, T / 128, 1), 256, 0, stream>>>(
        xn2, W1B, h1, b1, nullptr, T, 4 * H, H, 0, 0, 0);

    // ---- 12. out = x2 + h1 @ W2^T + b2 ----
    gemm_nt<0, true, false, false><<<dim3(H / 128, T / 128, 1), 256, 0, stream>>>(
        h1, W2B, (float*)d_out, b2, x2, T, H, 4 * H, 0, 0, 0);
}

// Round 7
// 1003.237 us; speedup vs baseline: 1.1292x; 1.1292x over previous
//
#include <hip/hip_runtime.h>
#include <hip/hip_bf16.h>
#include <cstdint>
#include <cstddef>

using bf16_t = __hip_bfloat16;
typedef __bf16 bf16x8 __attribute__((ext_vector_type(8)));
typedef __bf16 bf16x4 __attribute__((ext_vector_type(4)));
typedef float f32x4 __attribute__((ext_vector_type(4)));

#define DEVI static __device__ __forceinline__

DEVI float b2f(bf16_t v) { return __bfloat162float(v); }

DEVI float fsigmoid(float x) { return 1.0f / (1.0f + __expf(-x)); }
DEVI float fsilu(float x) { return x * fsigmoid(x); }

// fast erf, Abramowitz-Stegun 7.1.26 (max abs err 1.5e-7; bf16 eps is 4e-3)
DEVI float ferf(float x) {
    const float ax = fabsf(x);
    const float t = 1.0f / fmaf(0.3275911f, ax, 1.0f);
    float p = fmaf(1.061405429f, t, -1.453152027f);
    p = fmaf(p, t, 1.421413741f);
    p = fmaf(p, t, -0.284496736f);
    p = fmaf(p, t, 0.254829592f);
    p = p * t * __expf(-ax * ax);
    return copysignf(1.0f - p, x);
}
DEVI float fgelu(float x) { return 0.5f * x * (1.0f + ferf(x * 0.70710678118654752440f)); }

// async global->LDS, 16B per lane; LDS dest = wave-uniform base + lane*16
DEVI void g2l16(const bf16_t* g, bf16_t* l) {
    __builtin_amdgcn_global_load_lds(
        (const __attribute__((address_space(1))) void*)g,
        (__attribute__((address_space(3))) void*)l,
        16, 0, 0);
}

// ---------------------------------------------------------------------------
// NT GEMM, BK=64, 16x16x32 MFMA (R4-verified core: 0 bank conflicts,
// coalesced vector epilogue): C[M,N] = A[M,K] @ B[N,K]^T (+bias)(act)(+resid).
// bf16 row-major. M,N % 128 == 0, K % 64 == 0. Batched via grid.z.
// MFMA operands swapped (B-frag first) -> lane holds 4 consecutive cols.
// LDS 32 KB; XOR swizzle slot = chunk ^ (row & 7) on staging + frag reads.
// ACT: 0 none, 1 gelu, 3 qkv-mix (seg 0/1 silu + row-norm atomics,
//      seg 2 gelu, seg 3 sigmoid*0.9+0.1)
// QKVSPLIT: col segments of 1536 -> seg-major output (sC = seg stride).
// ---------------------------------------------------------------------------
template<int ACT, bool RESID, bool OUTBF, bool QKVSPLIT>
__global__ __launch_bounds__(256) void gemm_nt(
    const bf16_t* __restrict__ A, const bf16_t* __restrict__ B,
    void* __restrict__ Cout, const float* __restrict__ bias,
    const float* __restrict__ resid,
    float* __restrict__ normq, float* __restrict__ normk,
    int M, int N, int K, long long sA, long long sB, long long sC)
{
    __shared__ bf16_t As[128 * 64];
    __shared__ bf16_t Bs[128 * 64];

    const int t  = threadIdx.x;
    const int w  = t >> 6;
    const int ln = t & 63;
    const long long bz = blockIdx.z;
    A += bz * sA;
    B += bz * sB;
    const long long cbase = QKVSPLIT ? 0 : bz * sC;

    const int m0 = blockIdx.y * 128;
    const int n0 = blockIdx.x * 128;
    const int wm = (w >> 1) * 64;
    const int wn = (w & 1) * 64;

    f32x4 acc[4][4] = {};

    // staging: wave w, inst i (0..3) covers rows w*32 + i*8 .. +8
    const int sr = ln >> 3;            // row within octet
    const int sc = (ln & 7) ^ sr;      // swizzled global chunk (16B units)
    const bf16_t* Ap = A + (size_t)(m0 + w * 32 + sr) * K + sc * 8;
    const bf16_t* Bp = B + (size_t)(n0 + w * 32 + sr) * K + sc * 8;
    bf16_t* ldsA = &As[(w * 32) * 64];
    bf16_t* ldsB = &Bs[(w * 32) * 64];

    // fragment geometry
    const int fr = ln & 15;
    const int qd = ln >> 4;
    int roA[4], roB[4];
#pragma unroll
    for (int i = 0; i < 4; ++i) {
        roA[i] = (wm + i * 16 + fr) * 64;
        roB[i] = (wn + i * 16 + fr) * 64;
    }
    const int so0 = ((qd)     ^ (fr & 7)) * 8;
    const int so1 = ((4 + qd) ^ (fr & 7)) * 8;

    for (int k0 = 0; k0 < K; k0 += 64) {
#pragma unroll
        for (int i = 0; i < 4; ++i) {
            g2l16(Ap + (size_t)(i * 8) * K, ldsA + (i * 8) * 64);
            g2l16(Bp + (size_t)(i * 8) * K, ldsB + (i * 8) * 64);
        }
        Ap += 64; Bp += 64;
        __syncthreads();

        bf16x8 af[4], bfr[4];
#pragma unroll
        for (int i = 0; i < 4; ++i) {
            af[i]  = *(const bf16x8*)&As[roA[i] + so0];
            bfr[i] = *(const bf16x8*)&Bs[roB[i] + so0];
        }
#pragma unroll
        for (int mi = 0; mi < 4; ++mi)
#pragma unroll
            for (int ni = 0; ni < 4; ++ni)
                acc[mi][ni] = __builtin_amdgcn_mfma_f32_16x16x32_bf16(
                    bfr[ni], af[mi], acc[mi][ni], 0, 0, 0);
#pragma unroll
        for (int i = 0; i < 4; ++i) {
            af[i]  = *(const bf16x8*)&As[roA[i] + so1];
            bfr[i] = *(const bf16x8*)&Bs[roB[i] + so1];
        }
#pragma unroll
        for (int mi = 0; mi < 4; ++mi)
#pragma unroll
            for (int ni = 0; ni < 4; ++ni)
                acc[mi][ni] = __builtin_amdgcn_mfma_f32_16x16x32_bf16(
                    bfr[ni], af[mi], acc[mi][ni], 0, 0, 0);
        __syncthreads();
    }

    // epilogue: lane holds C[row = wm+mi*16+fr][cols = wn+ni*16+qd*4 .. +3]
    const int rb = qd * 4;
    const int seg = QKVSPLIT ? (n0 / 1536) : 0;
    f32x4 bias4[4];
#pragma unroll
    for (int ni = 0; ni < 4; ++ni) {
        f32x4 z = {};
        bias4[ni] = bias ? *(const f32x4*)&bias[n0 + wn + ni * 16 + rb] : z;
    }
#pragma unroll
    for (int mi = 0; mi < 4; ++mi) {
        const int row = m0 + wm + mi * 16 + fr;
        float s2 = 0.f;
#pragma unroll
        for (int ni = 0; ni < 4; ++ni) {
            const int col0 = n0 + wn + ni * 16 + rb;
            f32x4 v = acc[mi][ni] + bias4[ni];
            if constexpr (ACT == 1) {
#pragma unroll
                for (int r = 0; r < 4; ++r) v[r] = fgelu(v[r]);
            }
            if constexpr (ACT == 3) {
                if (seg <= 1) {
#pragma unroll
                    for (int r = 0; r < 4; ++r) v[r] = fsilu(v[r]);
                    s2 += v[0]*v[0] + v[1]*v[1] + v[2]*v[2] + v[3]*v[3];
                } else if (seg == 2) {
#pragma unroll
                    for (int r = 0; r < 4; ++r) v[r] = fgelu(v[r]);
                } else {
#pragma unroll
                    for (int r = 0; r < 4; ++r) v[r] = fsigmoid(v[r]) * 0.9f + 0.1f;
                }
            }
            long long off;
            if constexpr (QKVSPLIT) {
                off = (long long)seg * sC + (long long)row * 1536
                    + (col0 - seg * 1536);
            } else {
                off = cbase + (long long)row * N + col0;
            }
            if constexpr (RESID) v += *(const f32x4*)&resid[off];
            if constexpr (OUTBF) {
                bf16x4 o;
#pragma unroll
                for (int r = 0; r < 4; ++r) o[r] = (__bf16)v[r];
                *(bf16x4*)((bf16_t*)Cout + off) = o;
            } else {
                *(f32x4*)((float*)Cout + off) = v;
            }
        }
        if constexpr (ACT == 3) {
            if (seg <= 1) {
                // reduce Σsilu² across the 4 col-quads (lanes qd=0..3, same fr)
                s2 += __shfl_xor(s2, 16, 64);
                s2 += __shfl_xor(s2, 32, 64);
                if (qd == 0)
                    atomicAdd((seg == 0 ? normq : normk) + row, s2);
            }
        }
    }
}

// ---------------------------------------------------------------------------
// LayerNorm f32 -> bf16, n = NT*4, one block per row.
// ---------------------------------------------------------------------------
template<int NT>
__global__ __launch_bounds__(NT) void ln_v4(
    const float* __restrict__ x, const float* __restrict__ g,
    const float* __restrict__ b, bf16_t* __restrict__ out)
{
    constexpr int n = NT * 4;
    constexpr int NW = NT / 64;
    const int row = blockIdx.x, t = threadIdx.x;
    f32x4 v = *(const f32x4*)&x[(size_t)row * n + t * 4];
    float s  = v[0] + v[1] + v[2] + v[3];
    float ss = v[0]*v[0] + v[1]*v[1] + v[2]*v[2] + v[3]*v[3];
#pragma unroll
    for (int m = 32; m; m >>= 1) { s += __shfl_xor(s, m, 64); ss += __shfl_xor(ss, m, 64); }
    __shared__ float red[2 * NW];
    const int w = t >> 6;
    if ((t & 63) == 0) { red[w] = s; red[NW + w] = ss; }
    __syncthreads();
    s = 0.f; ss = 0.f;
#pragma unroll
    for (int i = 0; i < NW; ++i) { s += red[i]; ss += red[NW + i]; }
    const float mean = s / n;
    const float rstd = rsqrtf(ss / n - mean * mean + 1e-5f);
    const f32x4 gv = *(const f32x4*)&g[t * 4];
    const f32x4 bv = *(const f32x4*)&b[t * 4];
    bf16x4 o;
#pragma unroll
    for (int r = 0; r < 4; ++r)
        o[r] = (__bf16)((v[r] - mean) * rstd * gv[r] + bv[r]);
    *(bf16x4*)&out[(size_t)row * n + t * 4] = o;
}

// ---------------------------------------------------------------------------
// LayerNorm bf16 -> bf16 over 1536 (with scalar pre-scale). 192 thr x 8.
// ---------------------------------------------------------------------------
__global__ __launch_bounds__(192) void ln_bf16_1536(
    const bf16_t* __restrict__ x, const float* __restrict__ g,
    const float* __restrict__ b, bf16_t* __restrict__ out,
    const float* __restrict__ scale_ptr)
{
    const int row = blockIdx.x, t = threadIdx.x;
    const float scale = scale_ptr[0];
    const bf16x8 x8 = *(const bf16x8*)&x[(size_t)row * 1536 + t * 8];
    float v[8];
    float s = 0.f, ss = 0.f;
#pragma unroll
    for (int i = 0; i < 8; ++i) {
        v[i] = (float)x8[i] * scale;
        s += v[i]; ss += v[i] * v[i];
    }
#pragma unroll
    for (int m = 32; m; m >>= 1) { s += __shfl_xor(s, m, 64); ss += __shfl_xor(ss, m, 64); }
    __shared__ float red[6];
    const int w = t >> 6;
    if ((t & 63) == 0) { red[w] = s; red[3 + w] = ss; }
    __syncthreads();
    s  = red[0] + red[1] + red[2];
    ss = red[3] + red[4] + red[5];
    const float mean = s / 1536.f;
    const float rstd = rsqrtf(ss / 1536.f - mean * mean + 1e-5f);
    const f32x4 g0 = *(const f32x4*)&g[t * 8];
    const f32x4 g1 = *(const f32x4*)&g[t * 8 + 4];
    const f32x4 b0 = *(const f32x4*)&b[t * 8];
    const f32x4 b1 = *(const f32x4*)&b[t * 8 + 4];
    bf16x8 o;
#pragma unroll
    for (int r = 0; r < 4; ++r) {
        o[r]     = (__bf16)((v[r]     - mean) * rstd * g0[r] + b0[r]);
        o[r + 4] = (__bf16)((v[r + 4] - mean) * rstd * g1[r] + b1[r]);
    }
    *(bf16x8*)&out[(size_t)row * 1536 + t * 8] = o;
}

// ---------------------------------------------------------------------------
// Fused q+k coupling + depthwise conv (k=3, pad 1).
// Inputs qs,ks already silu'd; nq/nk hold Σsilu(q)², Σsilu(k)² per token.
// q1 = qs*rq + 0.1*ks; k1 = ks*rk + 0.1*q1; conv both;
// qc natural [B,L,E], kT transposed [B,E,L].
// grid (E/64, L/64, B), block 256; thread = 4e x 4l.
// ---------------------------------------------------------------------------
__global__ __launch_bounds__(256) void ac_qk(
    const bf16_t* __restrict__ qs, const bf16_t* __restrict__ ks,
    const float* __restrict__ nq, const float* __restrict__ nk,
    bf16_t* __restrict__ qc, bf16_t* __restrict__ kT,
    const float* __restrict__ cw)
{
    constexpr int L = 4096, E = 1536;
    const int b = blockIdx.z;
    const int e0 = blockIdx.x * 64, l0 = blockIdx.y * 64;
    const int t = threadIdx.x;
    const int e = e0 + (t & 15) * 4;
    const int lbase = l0 + (t >> 4) * 4;
    const size_t rowL = (size_t)b * L;

    float w0[4], w1[4], w2[4];
#pragma unroll
    for (int i = 0; i < 4; ++i) {
        w0[i] = cw[(e + i) * 3 + 0];
        w1[i] = cw[(e + i) * 3 + 1];
        w2[i] = cw[(e + i) * 3 + 2];
    }

    float sq[6][4], sk[6][4];
#pragma unroll
    for (int j = 0; j < 6; ++j) {
        const int l = lbase - 1 + j;
        if (l < 0 || l >= L) {
#pragma unroll
            for (int i = 0; i < 4; ++i) { sq[j][i] = 0.f; sk[j][i] = 0.f; }
            continue;
        }
        const size_t off = (rowL + l) * E + e;
        const bf16x4 q4 = *(const bf16x4*)&qs[off];
        const bf16x4 k4 = *(const bf16x4*)&ks[off];
        const float rq = 1.0f / fmaxf(sqrtf(nq[rowL + l]), 1e-12f);
        const float rk = 1.0f / fmaxf(sqrtf(nk[rowL + l]), 1e-12f);
#pragma unroll
        for (int i = 0; i < 4; ++i) {
            const float q1 = (float)q4[i] * rq + 0.1f * (float)k4[i];
            const float k1 = (float)k4[i] * rk + 0.1f * q1;
            sq[j][i] = q1; sk[j][i] = k1;
        }
    }

#pragma unroll
    for (int j = 0; j < 4; ++j) {
        bf16x4 oq;
#pragma unroll
        for (int i = 0; i < 4; ++i)
            oq[i] = (__bf16)(w0[i] * sq[j][i] + w1[i] * sq[j + 1][i] + w2[i] * sq[j + 2][i]);
        *(bf16x4*)&qc[(rowL + lbase + j) * E + e] = oq;
    }
#pragma unroll
    for (int i = 0; i < 4; ++i) {
        bf16x4 ok;
#pragma unroll
        for (int j = 0; j < 4; ++j)
            ok[j] = (__bf16)(w0[i] * sk[j][i] + w1[i] * sk[j + 1][i] + w2[i] * sk[j + 2][i]);
        *(bf16x4*)&kT[((size_t)b * E + e + i) * L + lbase] = ok;
    }
}

// ---------------------------------------------------------------------------
// v stream: conv(gelu'd v) * beta' -> transposed [B,E,L].
// ---------------------------------------------------------------------------
__global__ __launch_bounds__(256) void ac_v(
    const bf16_t* __restrict__ vg, const bf16_t* __restrict__ beta,
    bf16_t* __restrict__ vT, const float* __restrict__ cw)
{
    constexpr int L = 4096, E = 1536;
    const int b = blockIdx.z;
    const int e0 = blockIdx.x * 64, l0 = blockIdx.y * 64;
    const int t = threadIdx.x;
    const int e = e0 + (t & 15) * 4;
    const int lbase = l0 + (t >> 4) * 4;
    const size_t rowL = (size_t)b * L;

    float w0[4], w1[4], w2[4];
#pragma unroll
    for (int i = 0; i < 4; ++i) {
        w0[i] = cw[(e + i) * 3 + 0];
        w1[i] = cw[(e + i) * 3 + 1];
        w2[i] = cw[(e + i) * 3 + 2];
    }

    float s[6][4];
#pragma unroll
    for (int j = 0; j < 6; ++j) {
        const int l = lbase - 1 + j;
        if (l < 0 || l >= L) {
#pragma unroll
            for (int i = 0; i < 4; ++i) s[j][i] = 0.f;
            continue;
        }
        const bf16x4 v4 = *(const bf16x4*)&vg[(rowL + l) * E + e];
#pragma unroll
        for (int i = 0; i < 4; ++i) s[j][i] = (float)v4[i];
    }

    float o[4][4];
#pragma unroll
    for (int j = 0; j < 4; ++j) {
        const bf16x4 b4 = *(const bf16x4*)&beta[(rowL + lbase + j) * E + e];
#pragma unroll
        for (int i = 0; i < 4; ++i)
            o[j][i] = (w0[i] * s[j][i] + w1[i] * s[j + 1][i] + w2[i] * s[j + 2][i])
                      * (float)b4[i];
    }
#pragma unroll
    for (int i = 0; i < 4; ++i) {
        bf16x4 ov;
#pragma unroll
        for (int j = 0; j < 4; ++j) ov[j] = (__bf16)o[j][i];
        *(bf16x4*)&vT[((size_t)b * E + e + i) * L + lbase] = ov;
    }
}

// ---------------------------------------------------------------------------
// prep1: cast W_in|W_beta -> Wcat (contiguous), copy b_in|b_beta -> bcat.
// ---------------------------------------------------------------------------
__global__ __launch_bounds__(256) void prep1(
    const float* __restrict__ Win, const float* __restrict__ Wbeta,
    const float* __restrict__ bin, const float* __restrict__ bbeta,
    bf16_t* __restrict__ Wcat, float* __restrict__ bcat)
{
    constexpr int nWin4 = 3 * 1536 * 768 / 4;   // 884736
    constexpr int nWb4  = 1536 * 768 / 4;       // 294912
    const int i = blockIdx.x * 256 + threadIdx.x;
    if (i < nWin4) {
        const f32x4 v = ((const f32x4*)Win)[i];
        bf16x4 o;
#pragma unroll
        for (int r = 0; r < 4; ++r) o[r] = (__bf16)v[r];
        ((bf16x4*)Wcat)[i] = o;
    } else if (i < nWin4 + nWb4) {
        const f32x4 v = ((const f32x4*)Wbeta)[i - nWin4];
        bf16x4 o;
#pragma unroll
        for (int r = 0; r < 4; ++r) o[r] = (__bf16)v[r];
        ((bf16x4*)Wcat)[i] = o;
    } else {
        const int j = i - nWin4 - nWb4;         // 0..1535
        ((f32x4*)bcat)[j] = (j < 1152) ? ((const f32x4*)bin)[j]
                                       : ((const f32x4*)bbeta)[j - 1152];
    }
}

// prep2: cast W_out|W1|W2 into one contiguous bf16 region. 5760 blocks exact.
__global__ __launch_bounds__(256) void prep2(
    const float* __restrict__ Wout, const float* __restrict__ W1,
    const float* __restrict__ W2, bf16_t* __restrict__ dst)
{
    constexpr int n0 = 768 * 1536 / 4;          // 294912
    constexpr int n1 = n0 + 3072 * 768 / 4;     // + 589824
    const int i = blockIdx.x * 256 + threadIdx.x;
    const float* src;
    int j;
    if (i < n0)      { src = Wout; j = i; }
    else if (i < n1) { src = W1;   j = i - n0; }
    else             { src = W2;   j = i - n1; }
    const f32x4 v = ((const f32x4*)src)[j];
    bf16x4 o;
#pragma unroll
    for (int r = 0; r < 4; ++r) o[r] = (__bf16)v[r];
    ((bf16x4*)dst)[i] = o;
}

// diagnostic: report ws_size via absmax error channel
__global__ void diag_ws(float* o, float v) { o[threadIdx.x] = v; }

// ---------------------------------------------------------------------------

extern "C" void kernel_launch(void* const* d_in, const int* in_sizes, int n_in,
                              void* d_out, int out_size, void* d_ws, size_t ws_size,
                              hipStream_t stream)
{
    constexpr int B = 4, L = 4096, H = 768, E = 1536;
    constexpr int T = B * L;
    constexpr size_t SEGE = (size_t)T * E;
    constexpr size_t S    = SEGE * 2;            // 50,331,648 B
    constexpr size_t o_bcat  = 5 * S;
    constexpr size_t o_norms = o_bcat + 6144 * 4;
    constexpr size_t WS_NEED = o_norms + (size_t)T * 8;

    const float* x       = (const float*)d_in[0];
    const float* ln1_g   = (const float*)d_in[1];
    const float* ln1_b   = (const float*)d_in[2];
    const float* ln2_g   = (const float*)d_in[3];
    const float* ln2_b   = (const float*)d_in[4];
    const float* W_in    = (const float*)d_in[5];
    const float* b_in    = (const float*)d_in[6];
    const float* W_beta  = (const float*)d_in[7];
    const float* b_beta  = (const float*)d_in[8];
    const float* W_out   = (const float*)d_in[9];
    const float* b_out   = (const float*)d_in[10];
    const float* W1      = (const float*)d_in[11];
    const float* b1      = (const float*)d_in[12];
    const float* W2      = (const float*)d_in[13];
    const float* b2      = (const float*)d_in[14];
    const float* conv_w  = (const float*)d_in[15];
    const float* attn_sc = (const float*)d_in[16];

    if (ws_size < WS_NEED) {
        diag_ws<<<1, 256, 0, stream>>>((float*)d_out,
                                       10000.0f + (float)(ws_size >> 20));
        return;
    }

    char* ws = (char*)d_ws;
    bf16_t* slotA = (bf16_t*)(ws + 0 * S);   // qs -> state[0:18.9M] + weights@20M
    bf16_t* slotB = (bf16_t*)(ws + 1 * S);   // ks -> attn(bf16) -> xn2
    bf16_t* slotC = (bf16_t*)(ws + 2 * S);   // vg -> kT -> x2(f32)
    bf16_t* slotD = (bf16_t*)(ws + 3 * S);   // beta' -> qc -> h1[first half]
    bf16_t* slotE = (bf16_t*)(ws + 4 * S);   // Wcat+xn -> vT -> ln2o -> h1[2nd]
    float*  bcat  = (float*)(ws + o_bcat);
    float*  nq    = (float*)(ws + o_norms);          // [T] Σ silu(q)²
    float*  nk    = nq + T;                          // [T] Σ silu(k)²

    bf16_t* Wcat = slotE;                                           // 9.44 MB
    bf16_t* xn   = (bf16_t*)((char*)slotE + (size_t)6144 * H * 2);  // 25.2 MB

    bf16_t* vT    = slotE;                   // [B,E,L]
    bf16_t* kT    = slotC;                   // [B,E,L]
    bf16_t* qc    = slotD;                   // [B,L,E]
    bf16_t* state = slotA;                   // [B,E,E] 18.9 MB
    bf16_t* WoutB = (bf16_t*)((char*)slotA + (size_t)20 * 1024 * 1024);
    bf16_t* W1B   = WoutB + (size_t)H * E;
    bf16_t* W2B   = W1B + (size_t)4 * H * H;
    bf16_t* attn  = slotB;                   // [T,E] bf16
    bf16_t* ln2o  = slotE;                   // [T,E] bf16
    float*  x2    = (float*)slotC;           // [T,768] f32
    bf16_t* xn2   = slotB;                   // [T,768] bf16
    bf16_t* h1    = slotD;                   // [T,3072] bf16 spans D+E

    // ---- 0. weight prep (phase 1) + zero norm accumulators ----
    hipMemsetAsync(nq, 0, (size_t)T * 2 * sizeof(float), stream);
    prep1<<<4614, 256, 0, stream>>>(W_in, W_beta, b_in, b_beta, Wcat, bcat);

    // ---- 1. ln1(x) -> xn ----
    ln_v4<192><<<T, 192, 0, stream>>>(x, ln1_g, ln1_b, xn);

    // ---- 2. fused qkv+beta GEMM, activations + silu-l2 partials in epilogue ----
    gemm_nt<3, false, true, true><<<dim3(6144 / 128, T / 128, 1), 256, 0, stream>>>(
        xn, Wcat, slotA, bcat, nullptr, nq, nk, T, 6144, H, 0, 0, (long long)SEGE);

    // ---- 3. conv streams: v first (frees C,D), then fused q+k ----
    ac_v <<<dim3(E / 64, L / 64, B), 256, 0, stream>>>(slotC, slotD, vT, conv_w);
    ac_qk<<<dim3(E / 64, L / 64, B), 256, 0, stream>>>(slotA, slotB, nq, nk, qc, kT, conv_w);

    // ---- 4. weight prep (phase 2) into dead slot-A tail ----
    prep2<<<5760, 256, 0, stream>>>(W_out, W1, W2, WoutB);

    // ---- 5. state[b,e,f] = sum_l vnew[b,e,l] k[b,f,l] ----
    gemm_nt<0, false, true, false><<<dim3(E / 128, E / 128, B), 256, 0, stream>>>(
        vT, kT, state, nullptr, nullptr, nullptr, nullptr, E, E, L,
        (long long)E * L, (long long)E * L, (long long)E * E);

    // ---- 6. attn[b,l,e] = sum_f q[b,l,f] state[b,e,f] (bf16 out) ----
    gemm_nt<0, false, true, false><<<dim3(E / 128, L / 128, B), 256, 0, stream>>>(
        qc, state, attn, nullptr, nullptr, nullptr, nullptr, L, E, E,
        (long long)L * E, (long long)E * E, (long long)L * E);

    // ---- 7. ln2(attn * attn_scale) ----
    ln_bf16_1536<<<T, 192, 0, stream>>>(attn, ln2_g, ln2_b, ln2o, attn_sc);

    // ---- 8. x2 = x + ln2o @ W_out^T + b_out ----
    gemm_nt<0, true, false, false><<<dim3(H / 128, T / 128, 1), 256, 0, stream>>>(
        ln2o, WoutB, x2, b_out, x, nullptr, nullptr, T, H, E, 0, 0, 0);

    // ---- 9. ln1(x2) -> xn2 ----
    ln_v4<192><<<T, 192, 0, stream>>>(x2, ln1_g, ln1_b, xn2);

    // ---- 10. h1 = gelu(xn2 @ W1^T + b1) ----
    gemm_nt<1, false, true, false><<<dim3(4 * H / 128, T / 128, 1), 256, 0, stream>>>(
        xn2, W1B, h1, b1, nullptr, nullptr, nullptr, T, 4 * H, H, 0, 0, 0);

    // ---- 11. out = x2 + h1 @ W2^T + b2 ----
    gemm_nt<0, true, false, false><<<dim3(H / 128, T / 128, 1), 256, 0, stream>>>(
        h1, W2B, (float*)d_out, b2, x2, nullptr, nullptr, T, H, 4 * H, 0, 0, 0);
}